// Round 11
// baseline (122.704 us; speedup 1.0000x reference)
//
#include <hip/hip_runtime.h>
#include <math.h>

// UnrolledMeanShift R11 = MEASUREMENT ROUND.
// Kernel 1: exact R7 (proven 35.9us, passes) -> d_out.
// Kernel 2: diagnostic copy, stage once + compute-loop REP=4, results
// accumulated into d_ws (rep-varying z-init via ((px+2)^rep) so reps can't
// be LICM'd/DCE'd). Runs ~110-130us -> outranks the harness fillBuffer
// dispatches in rocprof top-5, finally giving VALUBusy / conflicts /
// occupancy for the compute loop. d_out untouched by kernel 2.

typedef _Float16 h2  __attribute__((ext_vector_type(2)));
typedef _Float16 h8  __attribute__((ext_vector_type(8)));
typedef unsigned int u4v __attribute__((ext_vector_type(4)));

constexpr int Dch  = 32;
constexpr int HH   = 256;
constexpr int WW   = 256;
constexpr int PADp = 2;
constexpr int BH   = 16;
constexpr int BW   = 16;
constexpr int TH   = BH + 2 * PADp;   // 20
constexpr int TWd  = BW + 2 * PADp;   // 20
constexpr int NPIX = TH * TWd;        // 400
constexpr int NPIXP = 402;            // plane-stride pad
constexpr int NCHK = 4;
constexpr int ITERS = 3;
constexpr int HWp  = HH * WW;
constexpr int NTHR = 512;

__device__ __forceinline__ float fdot2f(h2 a, h2 b, float c) {
    return __builtin_amdgcn_fdot2(a, b, c, false);
}

__device__ __forceinline__ float EXP2F(float x) {
#if __has_builtin(__builtin_amdgcn_exp2f)
    return __builtin_amdgcn_exp2f(x);
#else
    return __expf(x * 0.69314718055994531f);
#endif
}

__device__ __forceinline__ float qswap(float x) {
#if __has_builtin(__builtin_amdgcn_mov_dpp)
    return __int_as_float(
        __builtin_amdgcn_mov_dpp(__float_as_int(x), 0xB1, 0xF, 0xF, true));
#else
    return __shfl_xor(x, 1, 64);
#endif
}

__device__ __forceinline__ h2 as_h2(unsigned int x) {
    return __builtin_bit_cast(h2, x);
}

// shared staging routine (R3/R7-proven)
__device__ __forceinline__ void stage_tile(u4v (*tile)[NPIXP],
                                           const float* __restrict__ Eb,
                                           int oh, int ow, int tid)
{
    for (int job = tid; job < NCHK * NPIX; job += NTHR) {
        const int cc = job / NPIX;
        const int p  = job - cc * NPIX;
        const int tr = p / TWd;
        const int tc = p - tr * TWd;
        const int gh = oh + tr;
        const int gw = ow + tc;
        h8 v;
        if ((unsigned)gh < (unsigned)HH && (unsigned)gw < (unsigned)WW) {
            const float* p0 = Eb + (size_t)(8 * cc) * HWp + gh * WW + gw;
            #pragma unroll
            for (int k = 0; k < 8; ++k) v[k] = (_Float16)p0[k * HWp];
        } else {
            #pragma unroll
            for (int k = 0; k < 8; ++k) v[k] = (_Float16)0.f;
        }
        tile[cc][p] = __builtin_bit_cast(u4v, v);
    }
}

#define NBODY(NPI) do {                                                       \
        const u4v a  = tA[(NPI)];                                             \
        const u4v bq = tB[(NPI)];                                             \
        const h2 pa0 = as_h2(a[0]),  pa1 = as_h2(a[1]);                       \
        const h2 pa2 = as_h2(a[2]),  pa3 = as_h2(a[3]);                       \
        const h2 pb0 = as_h2(bq[0]), pb1 = as_h2(bq[1]);                      \
        const h2 pb2 = as_h2(bq[2]), pb3 = as_h2(bq[3]);                      \
        const h2 e0 = pa0 - z0, e1 = pa1 - z1, e2 = pa2 - z2, e3 = pa3 - z3;  \
        const h2 f0 = pb0 - z4, f1 = pb1 - z5, f2 = pb2 - z6, f3 = pb3 - z7;  \
        float s0 = fdot2f(e0, e0, 0.f);                                       \
        s0 = fdot2f(e1, e1, s0); s0 = fdot2f(e2, e2, s0);                     \
        s0 = fdot2f(e3, e3, s0);                                              \
        float s1 = fdot2f(f0, f0, 0.f);                                       \
        s1 = fdot2f(f1, f1, s1); s1 = fdot2f(f2, f2, s1);                     \
        s1 = fdot2f(f3, f3, s1);                                              \
        const float dp   = s0 + s1;                                           \
        const float dist = dp + qswap(dp);                                    \
        const float w    = EXP2F(dist * negNC);                               \
        den += w;                                                             \
        const _Float16 wh = (_Float16)w;                                      \
        const h2 w2v = {wh, wh};                                              \
        n0 += pa0 * w2v; n1 += pa1 * w2v; n2 += pa2 * w2v; n3 += pa3 * w2v;   \
        n4 += pb0 * w2v; n5 += pb1 * w2v; n6 += pb2 * w2v; n7 += pb3 * w2v;   \
    } while (0)

// ---------------- kernel 1: exact R7 (correctness + output) ----------------
__global__ __launch_bounds__(NTHR, 4)
void meanshift_kernel(const float* __restrict__ E,
                      const float* __restrict__ lbw,
                      float* __restrict__ out)
{
    __shared__ u4v tile[NCHK][NPIXP];

    const int bz   = blockIdx.z;
    const int oh   = blockIdx.y * BH - PADp;
    const int ow   = blockIdx.x * BW - PADp;
    const int tid  = threadIdx.x;
    const int half = tid & 1;
    const int pix  = tid >> 1;
    const int px   = pix & (BW - 1);
    const int py   = pix >> 4;
    const int c0   = 2 * half;

    const float bwv   = log1pf(__expf(lbw[0]));
    const float cc2   = 1.0f / (2.0f * bwv * bwv);
    const float negNC = -cc2 * 1.44269504f;

    const float* Eb = E + (size_t)bz * Dch * HWp;
    stage_tile(tile, Eb, oh, ow, tid);
    __syncthreads();

    const u4v* __restrict__ tA = tile[c0];
    const u4v* __restrict__ tB = tile[c0 + 1];

    const int myp = (py + PADp) * TWd + (px + PADp);
    h2 z0, z1, z2, z3, z4, z5, z6, z7;
    {
        const u4v ca = tA[myp];
        const u4v cb = tB[myp];
        z0 = as_h2(ca[0]); z1 = as_h2(ca[1]); z2 = as_h2(ca[2]); z3 = as_h2(ca[3]);
        z4 = as_h2(cb[0]); z5 = as_h2(cb[1]); z6 = as_h2(cb[2]); z7 = as_h2(cb[3]);
    }

    float* Ob = out + (size_t)bz * Dch * HWp;
    const int off    = (oh + PADp + py) * WW + (ow + PADp + px);
    const int chbase = 16 * half;

    #pragma unroll 1
    for (int it = 0; it < ITERS; ++it) {
        h2 n0 = {(_Float16)0.f, (_Float16)0.f};
        h2 n1 = n0, n2 = n0, n3 = n0, n4 = n0, n5 = n0, n6 = n0, n7 = n0;
        float den = 0.f;

        #pragma unroll 1
        for (int di = 0; di < 5; ++di) {
            const int rb = (py + di) * TWd + px;
            NBODY(rb + 0);
            NBODY(rb + 1);
            NBODY(rb + 2);
            NBODY(rb + 3);
            NBODY(rb + 4);
        }

        const float invf = 1.0f / (den + 1e-6f);
        if (it == ITERS - 1) {
#define WR(IDX, NV, EL) Ob[(size_t)(chbase + (IDX)) * HWp + off] = (float)NV[EL] * invf
            WR(0,  n0, 0); WR(1,  n0, 1); WR(2,  n1, 0); WR(3,  n1, 1);
            WR(4,  n2, 0); WR(5,  n2, 1); WR(6,  n3, 0); WR(7,  n3, 1);
            WR(8,  n4, 0); WR(9,  n4, 1); WR(10, n5, 0); WR(11, n5, 1);
            WR(12, n6, 0); WR(13, n6, 1); WR(14, n7, 0); WR(15, n7, 1);
#undef WR
        } else {
            const _Float16 ih = (_Float16)invf;
            const h2 iv = {ih, ih};
            z0 = n0 * iv; z1 = n1 * iv; z2 = n2 * iv; z3 = n3 * iv;
            z4 = n4 * iv; z5 = n5 * iv; z6 = n6 * iv; z7 = n7 * iv;
        }
    }
}

// ---------------- kernel 2: diagnostic, compute-loop x4 -> d_ws ------------
__global__ __launch_bounds__(NTHR, 4)
void meanshift_diag(const float* __restrict__ E,
                    const float* __restrict__ lbw,
                    float* __restrict__ ws)
{
    __shared__ u4v tile[NCHK][NPIXP];

    const int bz   = blockIdx.z;
    const int oh   = blockIdx.y * BH - PADp;
    const int ow   = blockIdx.x * BW - PADp;
    const int tid  = threadIdx.x;
    const int half = tid & 1;
    const int pix  = tid >> 1;
    const int px   = pix & (BW - 1);
    const int py   = pix >> 4;
    const int c0   = 2 * half;

    const float bwv   = log1pf(__expf(lbw[0]));
    const float cc2   = 1.0f / (2.0f * bwv * bwv);
    const float negNC = -cc2 * 1.44269504f;

    const float* Eb = E + (size_t)bz * Dch * HWp;
    stage_tile(tile, Eb, oh, ow, tid);
    __syncthreads();

    const u4v* __restrict__ tA = tile[c0];
    const u4v* __restrict__ tB = tile[c0 + 1];

    float a0 = 0.f, a1 = 0.f, a2 = 0.f, a3 = 0.f;
    float a4 = 0.f, a5 = 0.f, a6 = 0.f, a7 = 0.f;
    float a8 = 0.f, a9 = 0.f, a10 = 0.f, a11 = 0.f;
    float a12 = 0.f, a13 = 0.f, a14 = 0.f, a15 = 0.f;

    #pragma unroll 1
    for (int rep = 0; rep < 4; ++rep) {
        // rep-varying z-init (stays in data region cols 1..18) -> no LICM
        const int myp = (py + PADp) * TWd + ((px + PADp) ^ rep);
        h2 z0, z1, z2, z3, z4, z5, z6, z7;
        {
            const u4v ca = tA[myp];
            const u4v cb = tB[myp];
            z0 = as_h2(ca[0]); z1 = as_h2(ca[1]); z2 = as_h2(ca[2]); z3 = as_h2(ca[3]);
            z4 = as_h2(cb[0]); z5 = as_h2(cb[1]); z6 = as_h2(cb[2]); z7 = as_h2(cb[3]);
        }

        #pragma unroll 1
        for (int it = 0; it < ITERS; ++it) {
            h2 n0 = {(_Float16)0.f, (_Float16)0.f};
            h2 n1 = n0, n2 = n0, n3 = n0, n4 = n0, n5 = n0, n6 = n0, n7 = n0;
            float den = 0.f;

            #pragma unroll 1
            for (int di = 0; di < 5; ++di) {
                const int rb = (py + di) * TWd + px;
                NBODY(rb + 0);
                NBODY(rb + 1);
                NBODY(rb + 2);
                NBODY(rb + 3);
                NBODY(rb + 4);
            }

            const float invf = 1.0f / (den + 1e-6f);
            if (it == ITERS - 1) {
                a0  += (float)n0[0] * invf; a1  += (float)n0[1] * invf;
                a2  += (float)n1[0] * invf; a3  += (float)n1[1] * invf;
                a4  += (float)n2[0] * invf; a5  += (float)n2[1] * invf;
                a6  += (float)n3[0] * invf; a7  += (float)n3[1] * invf;
                a8  += (float)n4[0] * invf; a9  += (float)n4[1] * invf;
                a10 += (float)n5[0] * invf; a11 += (float)n5[1] * invf;
                a12 += (float)n6[0] * invf; a13 += (float)n6[1] * invf;
                a14 += (float)n7[0] * invf; a15 += (float)n7[1] * invf;
            } else {
                const _Float16 ih = (_Float16)invf;
                const h2 iv = {ih, ih};
                z0 = n0 * iv; z1 = n1 * iv; z2 = n2 * iv; z3 = n3 * iv;
                z4 = n4 * iv; z5 = n5 * iv; z6 = n6 * iv; z7 = n7 * iv;
            }
        }
    }

    float* Wb = ws + (size_t)bz * Dch * HWp;
    const int off    = (oh + PADp + py) * WW + (ow + PADp + px);
    const int chbase = 16 * half;
#define WA(IDX, V) Wb[(size_t)(chbase + (IDX)) * HWp + off] = V
    WA(0, a0);  WA(1, a1);  WA(2, a2);  WA(3, a3);
    WA(4, a4);  WA(5, a5);  WA(6, a6);  WA(7, a7);
    WA(8, a8);  WA(9, a9);  WA(10, a10); WA(11, a11);
    WA(12, a12); WA(13, a13); WA(14, a14); WA(15, a15);
#undef WA
}

extern "C" void kernel_launch(void* const* d_in, const int* in_sizes, int n_in,
                              void* d_out, int out_size, void* d_ws, size_t ws_size,
                              hipStream_t stream) {
    const float* E   = (const float*)d_in[0];
    const float* lbw = (const float*)d_in[1];
    float* out       = (float*)d_out;

    const int B = in_sizes[0] / (Dch * HWp);       // = 2
    dim3 grid(WW / BW, HH / BH, B);                // (16,16,2) = 512 blocks
    dim3 block(NTHR, 1, 1);
    hipLaunchKernelGGL(meanshift_kernel, grid, block, 0, stream, E, lbw, out);

    // diagnostic dispatch (top-5 rocprof target); needs out_size floats of ws
    if (ws_size >= (size_t)out_size * sizeof(float)) {
        hipLaunchKernelGGL(meanshift_diag, grid, block, 0, stream,
                           E, lbw, (float*)d_ws);
    }
}

// Round 12
// 109.890 us; speedup vs baseline: 1.1166x; 1.1166x over previous
//
#include <hip/hip_runtime.h>
#include <math.h>

// UnrolledMeanShift: B=2, D=32, H=W=256, K=5x5, 3 iterations.
// R12 = R7 skeleton (2 thr/pixel, 16 ch each, DPP pair-combine, fp16 LDS
// halo tile) with the weight-exponent computed by DOT-EXPANSION, fully
// constant-folded:  arg = A2*(p.z) - 0.5NC|p|^2*2 - 0.5NC|z|^2*2
//   = chainA(init=S_n) + chainB(init=mzz) summed across the lane pair.
// S_n = -0.5*NC*|p|^2 precomputed per tile pixel (LDS pass), hoisted into
// 25 INDIVIDUALLY-NAMED registers. mzz recomputed once per iter. zs = A2*z
// so the dot needs no post-multiply. w<=1 guaranteed -> packed-fp16 num
// (R5/R7-validated). w2v via single v_cvt_pkrtz.
// Per-neighbor VALU: 22 vs R7's 32 (R11 diag: VALUBusy 75% -> issue-bound).
// NO per-thread arrays (R4-R6 scratch lesson); di-loop fully unrolled with
// named S (R10 proved this shape stays in registers).

typedef _Float16 h2  __attribute__((ext_vector_type(2)));
typedef _Float16 h8  __attribute__((ext_vector_type(8)));
typedef unsigned int u4v __attribute__((ext_vector_type(4)));

constexpr int Dch  = 32;
constexpr int HH   = 256;
constexpr int WW   = 256;
constexpr int PADp = 2;
constexpr int BH   = 16;
constexpr int BW   = 16;
constexpr int TH   = BH + 2 * PADp;   // 20
constexpr int TWd  = BW + 2 * PADp;   // 20
constexpr int NPIX = TH * TWd;        // 400
constexpr int NPIXP = 402;            // plane-stride pad
constexpr int NCHK = 4;
constexpr int ITERS = 3;
constexpr int HWp  = HH * WW;
constexpr int NTHR = 512;

__device__ __forceinline__ float fdot2f(h2 a, h2 b, float c) {
    return __builtin_amdgcn_fdot2(a, b, c, false);
}

__device__ __forceinline__ float EXP2F(float x) {
#if __has_builtin(__builtin_amdgcn_exp2f)
    return __builtin_amdgcn_exp2f(x);
#else
    return __expf(x * 0.69314718055994531f);
#endif
}

// value from lane^1 (quad_perm [1,0,3,2]) — pure VALU, no LDS pipe
__device__ __forceinline__ float qswap(float x) {
#if __has_builtin(__builtin_amdgcn_mov_dpp)
    return __int_as_float(
        __builtin_amdgcn_mov_dpp(__float_as_int(x), 0xB1, 0xF, 0xF, true));
#else
    return __shfl_xor(x, 1, 64);
#endif
}

__device__ __forceinline__ h2 as_h2(unsigned int x) {
    return __builtin_bit_cast(h2, x);
}

// pack two f32 -> h2 with one v_cvt_pkrtz_f16_f32
__device__ __forceinline__ h2 pk2(float a, float b) {
#if __has_builtin(__builtin_amdgcn_cvt_pkrtz)
    return __builtin_bit_cast(h2, __builtin_amdgcn_cvt_pkrtz(a, b));
#else
    h2 r; r[0] = (_Float16)a; r[1] = (_Float16)b; return r;
#endif
}

__global__ __launch_bounds__(NTHR, 4)
void meanshift_kernel(const float* __restrict__ E,
                      const float* __restrict__ lbw,
                      float* __restrict__ out)
{
    __shared__ u4v  tile[NCHK][NPIXP];   // 25.7 KB
    __shared__ float sqv[NPIX];          // -0.5*NC*|p|^2 (full 32 ch)

    const int bz   = blockIdx.z;
    const int oh   = blockIdx.y * BH - PADp;
    const int ow   = blockIdx.x * BW - PADp;
    const int tid  = threadIdx.x;
    const int half = tid & 1;
    const int pix  = tid >> 1;
    const int px   = pix & (BW - 1);
    const int py   = pix >> 4;
    const int c0   = 2 * half;

    const float bwv = log1pf(__expf(lbw[0]));     // softplus
    const float cc2 = 1.0f / (2.0f * bwv * bwv);
    const float NCf = cc2 * 1.44269504f;          // w = 2^(-NC*dist^2)
    const float A2f = 2.0f * NCf;                 // coef on p.z
    const float MZC = -1.0f / (8.0f * NCf);       // mzz = MZC * |zs|^2_full

    const float* Eb = E + (size_t)bz * Dch * HWp;

    // ---- stage halo tile into LDS as fp16 (R3/R7-proven) ----
    for (int job = tid; job < NCHK * NPIX; job += NTHR) {
        const int cc = job / NPIX;
        const int p  = job - cc * NPIX;
        const int tr = p / TWd;
        const int tc = p - tr * TWd;
        const int gh = oh + tr;
        const int gw = ow + tc;
        h8 v;
        if ((unsigned)gh < (unsigned)HH && (unsigned)gw < (unsigned)WW) {
            const float* p0 = Eb + (size_t)(8 * cc) * HWp + gh * WW + gw;
            #pragma unroll
            for (int k = 0; k < 8; ++k) v[k] = (_Float16)p0[k * HWp];
        } else {
            #pragma unroll
            for (int k = 0; k < 8; ++k) v[k] = (_Float16)0.f;
        }
        tile[cc][p] = __builtin_bit_cast(u4v, v);
    }
    __syncthreads();

    // ---- precompute sqv[p] = -0.5*NC*|p|^2 (all 32 ch) per tile pixel ----
    for (int p = tid; p < NPIX; p += NTHR) {
        const u4v t0 = tile[0][p], t1 = tile[1][p];
        const u4v t2 = tile[2][p], t3 = tile[3][p];
        float a0 = 0.f, a1 = 0.f, a2 = 0.f, a3 = 0.f;
        #pragma unroll
        for (int j = 0; j < 4; ++j) {
            const h2 q0 = as_h2(t0[j]); a0 = fdot2f(q0, q0, a0);
            const h2 q1 = as_h2(t1[j]); a1 = fdot2f(q1, q1, a1);
            const h2 q2 = as_h2(t2[j]); a2 = fdot2f(q2, q2, a2);
            const h2 q3 = as_h2(t3[j]); a3 = fdot2f(q3, q3, a3);
        }
        sqv[p] = -0.5f * NCf * ((a0 + a1) + (a2 + a3));
    }
    __syncthreads();

    const u4v* __restrict__ tA = tile[c0];
    const u4v* __restrict__ tB = tile[c0 + 1];

    // ---- row bases + 25 NAMED hoisted S values (iteration-invariant) ----
    const int rb0 = (py + 0) * TWd + px;
    const int rb1 = (py + 1) * TWd + px;
    const int rb2 = (py + 2) * TWd + px;
    const int rb3 = (py + 3) * TWd + px;
    const int rb4 = (py + 4) * TWd + px;
    const float S00 = sqv[rb0+0], S01 = sqv[rb0+1], S02 = sqv[rb0+2], S03 = sqv[rb0+3], S04 = sqv[rb0+4];
    const float S10 = sqv[rb1+0], S11 = sqv[rb1+1], S12 = sqv[rb1+2], S13 = sqv[rb1+3], S14 = sqv[rb1+4];
    const float S20 = sqv[rb2+0], S21 = sqv[rb2+1], S22 = sqv[rb2+2], S23 = sqv[rb2+3], S24 = sqv[rb2+4];
    const float S30 = sqv[rb3+0], S31 = sqv[rb3+1], S32 = sqv[rb3+2], S33 = sqv[rb3+3], S34 = sqv[rb3+4];
    const float S40 = sqv[rb4+0], S41 = sqv[rb4+1], S42 = sqv[rb4+2], S43 = sqv[rb4+3], S44 = sqv[rb4+4];

    // ---- init zs = A2 * z(own pixel), my 16 channels ----
    h2 zs0, zs1, zs2, zs3, zs4, zs5, zs6, zs7;
    {
        const int myp = rb2 + 2;
        const u4v ca = tA[myp];
        const u4v cb = tB[myp];
        const h2 A2v = pk2(A2f, A2f);
        zs0 = as_h2(ca[0]) * A2v; zs1 = as_h2(ca[1]) * A2v;
        zs2 = as_h2(ca[2]) * A2v; zs3 = as_h2(ca[3]) * A2v;
        zs4 = as_h2(cb[0]) * A2v; zs5 = as_h2(cb[1]) * A2v;
        zs6 = as_h2(cb[2]) * A2v; zs7 = as_h2(cb[3]) * A2v;
    }

    float* Ob = out + (size_t)bz * Dch * HWp;
    const int off    = (oh + PADp + py) * WW + (ow + PADp + px);
    const int chbase = 16 * half;

#define NBODY(NPI, HS) do {                                                   \
        const u4v a  = tA[(NPI)];                                             \
        const u4v bq = tB[(NPI)];                                             \
        const h2 pa0 = as_h2(a[0]),  pa1 = as_h2(a[1]);                       \
        const h2 pa2 = as_h2(a[2]),  pa3 = as_h2(a[3]);                       \
        const h2 pb0 = as_h2(bq[0]), pb1 = as_h2(bq[1]);                      \
        const h2 pb2 = as_h2(bq[2]), pb3 = as_h2(bq[3]);                      \
        float s0 = fdot2f(pa0, zs0, (HS));                                    \
        s0 = fdot2f(pa1, zs1, s0); s0 = fdot2f(pa2, zs2, s0);                 \
        s0 = fdot2f(pa3, zs3, s0);                                            \
        float s1 = fdot2f(pb0, zs4, mzz);                                     \
        s1 = fdot2f(pb1, zs5, s1); s1 = fdot2f(pb2, zs6, s1);                 \
        s1 = fdot2f(pb3, zs7, s1);                                            \
        const float dp  = s0 + s1;                                            \
        const float arg = dp + qswap(dp);   /* = A2 p.z - NC|p|^2 - NC|z|^2 */\
        const float w   = EXP2F(arg);       /* <= ~1 */                       \
        den += w;                                                             \
        const h2 w2v = pk2(w, w);                                             \
        n0 += pa0 * w2v; n1 += pa1 * w2v; n2 += pa2 * w2v; n3 += pa3 * w2v;   \
        n4 += pb0 * w2v; n5 += pb1 * w2v; n6 += pb2 * w2v; n7 += pb3 * w2v;   \
    } while (0)

    #pragma unroll 1
    for (int it = 0; it < ITERS; ++it) {
        // mzz = -0.5*NC*|z|^2 (full 32 ch), from |zs|^2 = A2^2 |z|^2
        float mzz;
        {
            float q0 = fdot2f(zs0, zs0, 0.f);
            q0 = fdot2f(zs1, zs1, q0); q0 = fdot2f(zs2, zs2, q0);
            q0 = fdot2f(zs3, zs3, q0);
            float q1 = fdot2f(zs4, zs4, 0.f);
            q1 = fdot2f(zs5, zs5, q1); q1 = fdot2f(zs6, zs6, q1);
            q1 = fdot2f(zs7, zs7, q1);
            const float qs = q0 + q1;
            mzz = (qs + qswap(qs)) * MZC;
        }

        h2 n0 = {(_Float16)0.f, (_Float16)0.f};
        h2 n1 = n0, n2 = n0, n3 = n0, n4 = n0, n5 = n0, n6 = n0, n7 = n0;
        float den = 0.f;

        NBODY(rb0+0, S00); NBODY(rb0+1, S01); NBODY(rb0+2, S02); NBODY(rb0+3, S03); NBODY(rb0+4, S04);
        NBODY(rb1+0, S10); NBODY(rb1+1, S11); NBODY(rb1+2, S12); NBODY(rb1+3, S13); NBODY(rb1+4, S14);
        NBODY(rb2+0, S20); NBODY(rb2+1, S21); NBODY(rb2+2, S22); NBODY(rb2+3, S23); NBODY(rb2+4, S24);
        NBODY(rb3+0, S30); NBODY(rb3+1, S31); NBODY(rb3+2, S32); NBODY(rb3+3, S33); NBODY(rb3+4, S34);
        NBODY(rb4+0, S40); NBODY(rb4+1, S41); NBODY(rb4+2, S42); NBODY(rb4+3, S43); NBODY(rb4+4, S44);

        const float invf = 1.0f / (den + 1e-6f);
        if (it == ITERS - 1) {
#define WR(IDX, NV, EL) Ob[(size_t)(chbase + (IDX)) * HWp + off] = (float)NV[EL] * invf
            WR(0,  n0, 0); WR(1,  n0, 1); WR(2,  n1, 0); WR(3,  n1, 1);
            WR(4,  n2, 0); WR(5,  n2, 1); WR(6,  n3, 0); WR(7,  n3, 1);
            WR(8,  n4, 0); WR(9,  n4, 1); WR(10, n5, 0); WR(11, n5, 1);
            WR(12, n6, 0); WR(13, n6, 1); WR(14, n7, 0); WR(15, n7, 1);
#undef WR
        } else {
            // zs_new = A2 * (num * invf): fold A2 into the inverse
            const float ia = invf * A2f;
            const h2 iv = pk2(ia, ia);
            zs0 = n0 * iv; zs1 = n1 * iv; zs2 = n2 * iv; zs3 = n3 * iv;
            zs4 = n4 * iv; zs5 = n5 * iv; zs6 = n6 * iv; zs7 = n7 * iv;
        }
    }
#undef NBODY
}

extern "C" void kernel_launch(void* const* d_in, const int* in_sizes, int n_in,
                              void* d_out, int out_size, void* d_ws, size_t ws_size,
                              hipStream_t stream) {
    const float* E   = (const float*)d_in[0];
    const float* lbw = (const float*)d_in[1];
    float* out       = (float*)d_out;

    const int B = in_sizes[0] / (Dch * HWp);       // = 2
    dim3 grid(WW / BW, HH / BH, B);                // (16,16,2) = 512 blocks
    dim3 block(NTHR, 1, 1);                        // 512 threads (2/pixel)
    hipLaunchKernelGGL(meanshift_kernel, grid, block, 0, stream, E, lbw, out);
}

// Round 13
// 45.101 us; speedup vs baseline: 2.7206x; 2.4365x over previous
//
#include <hip/hip_runtime.h>
#include <math.h>

// UnrolledMeanShift: B=2, D=32, H=W=256, K=5x5, 3 iterations.
// R13 = R12's dot-expansion algorithm with the VGPR cap FIXED:
// __launch_bounds__(512, 2) -> 128-VGPR budget, 16 waves/CU (R7's best).
// R12 failed ONLY because (512,4) capped VGPR at 64 and the ~90-reg live
// set (25 named S + 8 zs + 8 n) spilled to scratch (FETCH 248MB, VALU 14%).
//
// arg = A2*(p.z) - NC|p|^2 - NC|z|^2 via two fdot2 chains with folded inits:
//   chainA init = S_n (= -0.5*NC*|p|^2, per-pixel, LDS-precomputed, hoisted
//   into 25 NAMED registers), chainB init = mzz (once per iter).
//   zs = A2*z so no post-multiply. w<=1 -> packed-fp16 numerator (R5/R7
//   validated). Per-neighbor VALU ~22 vs R7's 32 (R11: VALU-issue-bound 75%).

typedef _Float16 h2  __attribute__((ext_vector_type(2)));
typedef _Float16 h8  __attribute__((ext_vector_type(8)));
typedef unsigned int u4v __attribute__((ext_vector_type(4)));

constexpr int Dch  = 32;
constexpr int HH   = 256;
constexpr int WW   = 256;
constexpr int PADp = 2;
constexpr int BH   = 16;
constexpr int BW   = 16;
constexpr int TH   = BH + 2 * PADp;   // 20
constexpr int TWd  = BW + 2 * PADp;   // 20
constexpr int NPIX = TH * TWd;        // 400
constexpr int NPIXP = 402;            // plane-stride pad
constexpr int NCHK = 4;
constexpr int ITERS = 3;
constexpr int HWp  = HH * WW;
constexpr int NTHR = 512;

__device__ __forceinline__ float fdot2f(h2 a, h2 b, float c) {
    return __builtin_amdgcn_fdot2(a, b, c, false);
}

__device__ __forceinline__ float EXP2F(float x) {
#if __has_builtin(__builtin_amdgcn_exp2f)
    return __builtin_amdgcn_exp2f(x);
#else
    return __expf(x * 0.69314718055994531f);
#endif
}

// value from lane^1 (quad_perm [1,0,3,2]) — pure VALU, no LDS pipe
__device__ __forceinline__ float qswap(float x) {
#if __has_builtin(__builtin_amdgcn_mov_dpp)
    return __int_as_float(
        __builtin_amdgcn_mov_dpp(__float_as_int(x), 0xB1, 0xF, 0xF, true));
#else
    return __shfl_xor(x, 1, 64);
#endif
}

__device__ __forceinline__ h2 as_h2(unsigned int x) {
    return __builtin_bit_cast(h2, x);
}

// pack two f32 -> h2 with one v_cvt_pkrtz_f16_f32
__device__ __forceinline__ h2 pk2(float a, float b) {
#if __has_builtin(__builtin_amdgcn_cvt_pkrtz)
    return __builtin_bit_cast(h2, __builtin_amdgcn_cvt_pkrtz(a, b));
#else
    h2 r; r[0] = (_Float16)a; r[1] = (_Float16)b; return r;
#endif
}

__global__ __launch_bounds__(NTHR, 2)
void meanshift_kernel(const float* __restrict__ E,
                      const float* __restrict__ lbw,
                      float* __restrict__ out)
{
    __shared__ u4v  tile[NCHK][NPIXP];   // 25.7 KB
    __shared__ float sqv[NPIX];          // -0.5*NC*|p|^2 (full 32 ch)

    const int bz   = blockIdx.z;
    const int oh   = blockIdx.y * BH - PADp;
    const int ow   = blockIdx.x * BW - PADp;
    const int tid  = threadIdx.x;
    const int half = tid & 1;
    const int pix  = tid >> 1;
    const int px   = pix & (BW - 1);
    const int py   = pix >> 4;
    const int c0   = 2 * half;

    const float bwv = log1pf(__expf(lbw[0]));     // softplus
    const float cc2 = 1.0f / (2.0f * bwv * bwv);
    const float NCf = cc2 * 1.44269504f;          // w = 2^(-NC*dist^2)
    const float A2f = 2.0f * NCf;                 // coef on p.z
    const float MZC = -1.0f / (8.0f * NCf);       // mzz = MZC * |zs|^2_full

    const float* Eb = E + (size_t)bz * Dch * HWp;

    // ---- stage halo tile into LDS as fp16 (R3/R7-proven) ----
    for (int job = tid; job < NCHK * NPIX; job += NTHR) {
        const int cc = job / NPIX;
        const int p  = job - cc * NPIX;
        const int tr = p / TWd;
        const int tc = p - tr * TWd;
        const int gh = oh + tr;
        const int gw = ow + tc;
        h8 v;
        if ((unsigned)gh < (unsigned)HH && (unsigned)gw < (unsigned)WW) {
            const float* p0 = Eb + (size_t)(8 * cc) * HWp + gh * WW + gw;
            #pragma unroll
            for (int k = 0; k < 8; ++k) v[k] = (_Float16)p0[k * HWp];
        } else {
            #pragma unroll
            for (int k = 0; k < 8; ++k) v[k] = (_Float16)0.f;
        }
        tile[cc][p] = __builtin_bit_cast(u4v, v);
    }
    __syncthreads();

    // ---- precompute sqv[p] = -0.5*NC*|p|^2 (all 32 ch) per tile pixel ----
    for (int p = tid; p < NPIX; p += NTHR) {
        const u4v t0 = tile[0][p], t1 = tile[1][p];
        const u4v t2 = tile[2][p], t3 = tile[3][p];
        float a0 = 0.f, a1 = 0.f, a2 = 0.f, a3 = 0.f;
        #pragma unroll
        for (int j = 0; j < 4; ++j) {
            const h2 q0 = as_h2(t0[j]); a0 = fdot2f(q0, q0, a0);
            const h2 q1 = as_h2(t1[j]); a1 = fdot2f(q1, q1, a1);
            const h2 q2 = as_h2(t2[j]); a2 = fdot2f(q2, q2, a2);
            const h2 q3 = as_h2(t3[j]); a3 = fdot2f(q3, q3, a3);
        }
        sqv[p] = -0.5f * NCf * ((a0 + a1) + (a2 + a3));
    }
    __syncthreads();

    const u4v* __restrict__ tA = tile[c0];
    const u4v* __restrict__ tB = tile[c0 + 1];

    // ---- row bases + 25 NAMED hoisted S values (iteration-invariant) ----
    const int rb0 = (py + 0) * TWd + px;
    const int rb1 = (py + 1) * TWd + px;
    const int rb2 = (py + 2) * TWd + px;
    const int rb3 = (py + 3) * TWd + px;
    const int rb4 = (py + 4) * TWd + px;
    const float S00 = sqv[rb0+0], S01 = sqv[rb0+1], S02 = sqv[rb0+2], S03 = sqv[rb0+3], S04 = sqv[rb0+4];
    const float S10 = sqv[rb1+0], S11 = sqv[rb1+1], S12 = sqv[rb1+2], S13 = sqv[rb1+3], S14 = sqv[rb1+4];
    const float S20 = sqv[rb2+0], S21 = sqv[rb2+1], S22 = sqv[rb2+2], S23 = sqv[rb2+3], S24 = sqv[rb2+4];
    const float S30 = sqv[rb3+0], S31 = sqv[rb3+1], S32 = sqv[rb3+2], S33 = sqv[rb3+3], S34 = sqv[rb3+4];
    const float S40 = sqv[rb4+0], S41 = sqv[rb4+1], S42 = sqv[rb4+2], S43 = sqv[rb4+3], S44 = sqv[rb4+4];

    // ---- init zs = A2 * z(own pixel), my 16 channels ----
    h2 zs0, zs1, zs2, zs3, zs4, zs5, zs6, zs7;
    {
        const int myp = rb2 + 2;
        const u4v ca = tA[myp];
        const u4v cb = tB[myp];
        const h2 A2v = pk2(A2f, A2f);
        zs0 = as_h2(ca[0]) * A2v; zs1 = as_h2(ca[1]) * A2v;
        zs2 = as_h2(ca[2]) * A2v; zs3 = as_h2(ca[3]) * A2v;
        zs4 = as_h2(cb[0]) * A2v; zs5 = as_h2(cb[1]) * A2v;
        zs6 = as_h2(cb[2]) * A2v; zs7 = as_h2(cb[3]) * A2v;
    }

    float* Ob = out + (size_t)bz * Dch * HWp;
    const int off    = (oh + PADp + py) * WW + (ow + PADp + px);
    const int chbase = 16 * half;

#define NBODY(NPI, HS) do {                                                   \
        const u4v a  = tA[(NPI)];                                             \
        const u4v bq = tB[(NPI)];                                             \
        const h2 pa0 = as_h2(a[0]),  pa1 = as_h2(a[1]);                       \
        const h2 pa2 = as_h2(a[2]),  pa3 = as_h2(a[3]);                       \
        const h2 pb0 = as_h2(bq[0]), pb1 = as_h2(bq[1]);                      \
        const h2 pb2 = as_h2(bq[2]), pb3 = as_h2(bq[3]);                      \
        float s0 = fdot2f(pa0, zs0, (HS));                                    \
        s0 = fdot2f(pa1, zs1, s0); s0 = fdot2f(pa2, zs2, s0);                 \
        s0 = fdot2f(pa3, zs3, s0);                                            \
        float s1 = fdot2f(pb0, zs4, mzz);                                     \
        s1 = fdot2f(pb1, zs5, s1); s1 = fdot2f(pb2, zs6, s1);                 \
        s1 = fdot2f(pb3, zs7, s1);                                            \
        const float dp  = s0 + s1;                                            \
        const float arg = dp + qswap(dp);   /* = A2 p.z - NC|p|^2 - NC|z|^2 */\
        const float w   = EXP2F(arg);       /* <= ~1 */                       \
        den += w;                                                             \
        const h2 w2v = pk2(w, w);                                             \
        n0 += pa0 * w2v; n1 += pa1 * w2v; n2 += pa2 * w2v; n3 += pa3 * w2v;   \
        n4 += pb0 * w2v; n5 += pb1 * w2v; n6 += pb2 * w2v; n7 += pb3 * w2v;   \
    } while (0)

    #pragma unroll 1
    for (int it = 0; it < ITERS; ++it) {
        // mzz = -0.5*NC*|z|^2 (full 32 ch), from |zs|^2 = A2^2 |z|^2
        float mzz;
        {
            float q0 = fdot2f(zs0, zs0, 0.f);
            q0 = fdot2f(zs1, zs1, q0); q0 = fdot2f(zs2, zs2, q0);
            q0 = fdot2f(zs3, zs3, q0);
            float q1 = fdot2f(zs4, zs4, 0.f);
            q1 = fdot2f(zs5, zs5, q1); q1 = fdot2f(zs6, zs6, q1);
            q1 = fdot2f(zs7, zs7, q1);
            const float qs = q0 + q1;
            mzz = (qs + qswap(qs)) * MZC;
        }

        h2 n0 = {(_Float16)0.f, (_Float16)0.f};
        h2 n1 = n0, n2 = n0, n3 = n0, n4 = n0, n5 = n0, n6 = n0, n7 = n0;
        float den = 0.f;

        NBODY(rb0+0, S00); NBODY(rb0+1, S01); NBODY(rb0+2, S02); NBODY(rb0+3, S03); NBODY(rb0+4, S04);
        NBODY(rb1+0, S10); NBODY(rb1+1, S11); NBODY(rb1+2, S12); NBODY(rb1+3, S13); NBODY(rb1+4, S14);
        NBODY(rb2+0, S20); NBODY(rb2+1, S21); NBODY(rb2+2, S22); NBODY(rb2+3, S23); NBODY(rb2+4, S24);
        NBODY(rb3+0, S30); NBODY(rb3+1, S31); NBODY(rb3+2, S32); NBODY(rb3+3, S33); NBODY(rb3+4, S34);
        NBODY(rb4+0, S40); NBODY(rb4+1, S41); NBODY(rb4+2, S42); NBODY(rb4+3, S43); NBODY(rb4+4, S44);

        const float invf = 1.0f / (den + 1e-6f);
        if (it == ITERS - 1) {
#define WR(IDX, NV, EL) Ob[(size_t)(chbase + (IDX)) * HWp + off] = (float)NV[EL] * invf
            WR(0,  n0, 0); WR(1,  n0, 1); WR(2,  n1, 0); WR(3,  n1, 1);
            WR(4,  n2, 0); WR(5,  n2, 1); WR(6,  n3, 0); WR(7,  n3, 1);
            WR(8,  n4, 0); WR(9,  n4, 1); WR(10, n5, 0); WR(11, n5, 1);
            WR(12, n6, 0); WR(13, n6, 1); WR(14, n7, 0); WR(15, n7, 1);
#undef WR
        } else {
            // zs_new = A2 * (num * invf): fold A2 into the inverse
            const float ia = invf * A2f;
            const h2 iv = pk2(ia, ia);
            zs0 = n0 * iv; zs1 = n1 * iv; zs2 = n2 * iv; zs3 = n3 * iv;
            zs4 = n4 * iv; zs5 = n5 * iv; zs6 = n6 * iv; zs7 = n7 * iv;
        }
    }
#undef NBODY
}

extern "C" void kernel_launch(void* const* d_in, const int* in_sizes, int n_in,
                              void* d_out, int out_size, void* d_ws, size_t ws_size,
                              hipStream_t stream) {
    const float* E   = (const float*)d_in[0];
    const float* lbw = (const float*)d_in[1];
    float* out       = (float*)d_out;

    const int B = in_sizes[0] / (Dch * HWp);       // = 2
    dim3 grid(WW / BW, HH / BH, B);                // (16,16,2) = 512 blocks
    dim3 block(NTHR, 1, 1);                        // 512 threads (2/pixel)
    hipLaunchKernelGGL(meanshift_kernel, grid, block, 0, stream, E, lbw, out);
}

// Round 14
// 32.198 us; speedup vs baseline: 3.8110x; 1.4008x over previous
//
#include <hip/hip_runtime.h>
#include <math.h>

// UnrolledMeanShift: B=2, D=32, H=W=256, K=5x5, 3 iterations.
// R14 = R7 skeleton (2 thr/pixel, 16 ch each, DPP pair-combine, fp16 LDS
// halo, launch_bounds(512,4), rolled di-loop) + dot-expansion weight:
//   arg = A2*(p.z) - NC|p|^2 - NC|z|^2
// chain-A init = S (read per-neighbor from LDS sqv[] -- NOT 25 registers;
// R12/R13 proved that spills at any cap), chain-B init = mzz (once/iter).
// zs = A2*z folds the post-multiply. w<=1 -> packed-fp16 numerator
// (R5/R7-validated). ~21 VALU/neighbor vs R7's 32 (R11: VALU 75% busy).

typedef _Float16 h2  __attribute__((ext_vector_type(2)));
typedef _Float16 h8  __attribute__((ext_vector_type(8)));
typedef unsigned int u4v __attribute__((ext_vector_type(4)));

constexpr int Dch  = 32;
constexpr int HH   = 256;
constexpr int WW   = 256;
constexpr int PADp = 2;
constexpr int BH   = 16;
constexpr int BW   = 16;
constexpr int TH   = BH + 2 * PADp;   // 20
constexpr int TWd  = BW + 2 * PADp;   // 20
constexpr int NPIX = TH * TWd;        // 400
constexpr int NPIXP = 402;            // plane-stride pad
constexpr int NCHK = 4;
constexpr int ITERS = 3;
constexpr int HWp  = HH * WW;
constexpr int NTHR = 512;

__device__ __forceinline__ float fdot2f(h2 a, h2 b, float c) {
    return __builtin_amdgcn_fdot2(a, b, c, false);
}

__device__ __forceinline__ float EXP2F(float x) {
#if __has_builtin(__builtin_amdgcn_exp2f)
    return __builtin_amdgcn_exp2f(x);
#else
    return __expf(x * 0.69314718055994531f);
#endif
}

// value from lane^1 (quad_perm [1,0,3,2]) — pure VALU, no LDS pipe
__device__ __forceinline__ float qswap(float x) {
#if __has_builtin(__builtin_amdgcn_mov_dpp)
    return __int_as_float(
        __builtin_amdgcn_mov_dpp(__float_as_int(x), 0xB1, 0xF, 0xF, true));
#else
    return __shfl_xor(x, 1, 64);
#endif
}

__device__ __forceinline__ h2 as_h2(unsigned int x) {
    return __builtin_bit_cast(h2, x);
}

// pack two f32 -> h2 with one v_cvt_pkrtz_f16_f32
__device__ __forceinline__ h2 pk2(float a, float b) {
#if __has_builtin(__builtin_amdgcn_cvt_pkrtz)
    return __builtin_bit_cast(h2, __builtin_amdgcn_cvt_pkrtz(a, b));
#else
    h2 r; r[0] = (_Float16)a; r[1] = (_Float16)b; return r;
#endif
}

__global__ __launch_bounds__(NTHR, 4)
void meanshift_kernel(const float* __restrict__ E,
                      const float* __restrict__ lbw,
                      float* __restrict__ out)
{
    __shared__ u4v  tile[NCHK][NPIXP];   // 25.7 KB
    __shared__ float sqv[NPIX];          // -0.5*NC*|p|^2 (full 32 ch)

    const int bz   = blockIdx.z;
    const int oh   = blockIdx.y * BH - PADp;
    const int ow   = blockIdx.x * BW - PADp;
    const int tid  = threadIdx.x;
    const int half = tid & 1;
    const int pix  = tid >> 1;
    const int px   = pix & (BW - 1);
    const int py   = pix >> 4;
    const int c0   = 2 * half;

    const float bwv = log1pf(__expf(lbw[0]));     // softplus
    const float cc2 = 1.0f / (2.0f * bwv * bwv);
    const float NCf = cc2 * 1.44269504f;          // w = 2^(-NC*dist^2)
    const float A2f = 2.0f * NCf;                 // coef on p.z
    const float MZC = -1.0f / (8.0f * NCf);       // mzz = MZC * |zs|^2_full

    const float* Eb = E + (size_t)bz * Dch * HWp;

    // ---- stage halo tile into LDS as fp16 (R3/R7-proven) ----
    for (int job = tid; job < NCHK * NPIX; job += NTHR) {
        const int cc = job / NPIX;
        const int p  = job - cc * NPIX;
        const int tr = p / TWd;
        const int tc = p - tr * TWd;
        const int gh = oh + tr;
        const int gw = ow + tc;
        h8 v;
        if ((unsigned)gh < (unsigned)HH && (unsigned)gw < (unsigned)WW) {
            const float* p0 = Eb + (size_t)(8 * cc) * HWp + gh * WW + gw;
            #pragma unroll
            for (int k = 0; k < 8; ++k) v[k] = (_Float16)p0[k * HWp];
        } else {
            #pragma unroll
            for (int k = 0; k < 8; ++k) v[k] = (_Float16)0.f;
        }
        tile[cc][p] = __builtin_bit_cast(u4v, v);
    }
    __syncthreads();

    // ---- precompute sqv[p] = -0.5*NC*|p|^2 (all 32 ch) per tile pixel ----
    for (int p = tid; p < NPIX; p += NTHR) {
        const u4v t0 = tile[0][p], t1 = tile[1][p];
        const u4v t2 = tile[2][p], t3 = tile[3][p];
        float a0 = 0.f, a1 = 0.f, a2 = 0.f, a3 = 0.f;
        #pragma unroll
        for (int j = 0; j < 4; ++j) {
            const h2 q0 = as_h2(t0[j]); a0 = fdot2f(q0, q0, a0);
            const h2 q1 = as_h2(t1[j]); a1 = fdot2f(q1, q1, a1);
            const h2 q2 = as_h2(t2[j]); a2 = fdot2f(q2, q2, a2);
            const h2 q3 = as_h2(t3[j]); a3 = fdot2f(q3, q3, a3);
        }
        sqv[p] = -0.5f * NCf * ((a0 + a1) + (a2 + a3));
    }
    __syncthreads();

    const u4v* __restrict__ tA = tile[c0];
    const u4v* __restrict__ tB = tile[c0 + 1];

    // ---- init zs = A2 * z(own pixel), my 16 channels ----
    h2 zs0, zs1, zs2, zs3, zs4, zs5, zs6, zs7;
    {
        const int myp = (py + PADp) * TWd + (px + PADp);
        const u4v ca = tA[myp];
        const u4v cb = tB[myp];
        const h2 A2v = pk2(A2f, A2f);
        zs0 = as_h2(ca[0]) * A2v; zs1 = as_h2(ca[1]) * A2v;
        zs2 = as_h2(ca[2]) * A2v; zs3 = as_h2(ca[3]) * A2v;
        zs4 = as_h2(cb[0]) * A2v; zs5 = as_h2(cb[1]) * A2v;
        zs6 = as_h2(cb[2]) * A2v; zs7 = as_h2(cb[3]) * A2v;
    }

    float* Ob = out + (size_t)bz * Dch * HWp;
    const int off    = (oh + PADp + py) * WW + (ow + PADp + px);
    const int chbase = 16 * half;

#define NBODY(NPI) do {                                                       \
        const u4v a  = tA[(NPI)];                                             \
        const u4v bq = tB[(NPI)];                                             \
        const float Sv = sqv[(NPI)];                                          \
        const h2 pa0 = as_h2(a[0]),  pa1 = as_h2(a[1]);                       \
        const h2 pa2 = as_h2(a[2]),  pa3 = as_h2(a[3]);                       \
        const h2 pb0 = as_h2(bq[0]), pb1 = as_h2(bq[1]);                      \
        const h2 pb2 = as_h2(bq[2]), pb3 = as_h2(bq[3]);                      \
        float s0 = fdot2f(pa0, zs0, Sv);                                      \
        s0 = fdot2f(pa1, zs1, s0); s0 = fdot2f(pa2, zs2, s0);                 \
        s0 = fdot2f(pa3, zs3, s0);                                            \
        float s1 = fdot2f(pb0, zs4, mzz);                                     \
        s1 = fdot2f(pb1, zs5, s1); s1 = fdot2f(pb2, zs6, s1);                 \
        s1 = fdot2f(pb3, zs7, s1);                                            \
        const float dp  = s0 + s1;                                            \
        const float arg = dp + qswap(dp);   /* A2 p.z - NC|p|^2 - NC|z|^2 */  \
        const float w   = EXP2F(arg);       /* <= ~1 */                       \
        den += w;                                                             \
        const h2 w2v = pk2(w, w);                                             \
        n0 += pa0 * w2v; n1 += pa1 * w2v; n2 += pa2 * w2v; n3 += pa3 * w2v;   \
        n4 += pb0 * w2v; n5 += pb1 * w2v; n6 += pb2 * w2v; n7 += pb3 * w2v;   \
    } while (0)

    #pragma unroll 1
    for (int it = 0; it < ITERS; ++it) {
        // mzz = -0.5*NC*|z|^2 (full 32 ch), from |zs|^2 = A2^2 |z|^2
        float mzz;
        {
            float q0 = fdot2f(zs0, zs0, 0.f);
            q0 = fdot2f(zs1, zs1, q0); q0 = fdot2f(zs2, zs2, q0);
            q0 = fdot2f(zs3, zs3, q0);
            float q1 = fdot2f(zs4, zs4, 0.f);
            q1 = fdot2f(zs5, zs5, q1); q1 = fdot2f(zs6, zs6, q1);
            q1 = fdot2f(zs7, zs7, q1);
            const float qs = q0 + q1;
            mzz = (qs + qswap(qs)) * MZC;
        }

        h2 n0 = {(_Float16)0.f, (_Float16)0.f};
        h2 n1 = n0, n2 = n0, n3 = n0, n4 = n0, n5 = n0, n6 = n0, n7 = n0;
        float den = 0.f;

        #pragma unroll 1
        for (int di = 0; di < 5; ++di) {
            const int rb = (py + di) * TWd + px;
            NBODY(rb + 0);
            NBODY(rb + 1);
            NBODY(rb + 2);
            NBODY(rb + 3);
            NBODY(rb + 4);
        }

        const float invf = 1.0f / (den + 1e-6f);
        if (it == ITERS - 1) {
#define WR(IDX, NV, EL) Ob[(size_t)(chbase + (IDX)) * HWp + off] = (float)NV[EL] * invf
            WR(0,  n0, 0); WR(1,  n0, 1); WR(2,  n1, 0); WR(3,  n1, 1);
            WR(4,  n2, 0); WR(5,  n2, 1); WR(6,  n3, 0); WR(7,  n3, 1);
            WR(8,  n4, 0); WR(9,  n4, 1); WR(10, n5, 0); WR(11, n5, 1);
            WR(12, n6, 0); WR(13, n6, 1); WR(14, n7, 0); WR(15, n7, 1);
#undef WR
        } else {
            // zs_new = A2 * (num * invf): fold A2 into the inverse
            const float ia = invf * A2f;
            const h2 iv = pk2(ia, ia);
            zs0 = n0 * iv; zs1 = n1 * iv; zs2 = n2 * iv; zs3 = n3 * iv;
            zs4 = n4 * iv; zs5 = n5 * iv; zs6 = n6 * iv; zs7 = n7 * iv;
        }
    }
#undef NBODY
}

extern "C" void kernel_launch(void* const* d_in, const int* in_sizes, int n_in,
                              void* d_out, int out_size, void* d_ws, size_t ws_size,
                              hipStream_t stream) {
    const float* E   = (const float*)d_in[0];
    const float* lbw = (const float*)d_in[1];
    float* out       = (float*)d_out;

    const int B = in_sizes[0] / (Dch * HWp);       // = 2
    dim3 grid(WW / BW, HH / BH, B);                // (16,16,2) = 512 blocks
    dim3 block(NTHR, 1, 1);                        // 512 threads (2/pixel)
    hipLaunchKernelGGL(meanshift_kernel, grid, block, 0, stream, E, lbw, out);
}

// Round 15
// 31.272 us; speedup vs baseline: 3.9237x; 1.0296x over previous
//
#include <hip/hip_runtime.h>
#include <math.h>

// UnrolledMeanShift: B=2, D=32, H=W=256, K=5x5, 3 iterations.
// R15 = R14's compute loop (dot-expansion, LDS-resident S, packed-fp16 num,
// 2 thr/pixel + DPP pair-combine) + VECTORIZED STAGING:
// R11-diag decomposition showed staging ~15us of R14's 32us (8 scalar f32
// loads strided 256KB per LDS word). Now: stage 24 cols so float4 loads are
// 16B-aligned; job = (plane,row,colgroup) = 8 x float4 loads (8ch x 4px),
// register transpose via v_cvt_pkrtz, 4 x ds_write_b128. 480 jobs = 1/thread.
// Edge groups: predicated per-element path (zero-fill = reference padding).

typedef _Float16 h2  __attribute__((ext_vector_type(2)));
typedef unsigned int u4v __attribute__((ext_vector_type(4)));

constexpr int Dch  = 32;
constexpr int HH   = 256;
constexpr int WW   = 256;
constexpr int PADp = 2;
constexpr int BH   = 16;
constexpr int BW   = 16;
constexpr int THs  = 20;              // staged rows (rel -2..17)
constexpr int RSTR = 25;              // staged row stride: 24 cols + 1 pad
constexpr int PSTR = THs * RSTR + 1;  // 501 words plane stride
constexpr int NJOB = 4 * THs * 6;     // 480 staging jobs
constexpr int ITERS = 3;
constexpr int HWp  = HH * WW;
constexpr int NTHR = 512;

__device__ __forceinline__ float fdot2f(h2 a, h2 b, float c) {
    return __builtin_amdgcn_fdot2(a, b, c, false);
}

__device__ __forceinline__ float EXP2F(float x) {
#if __has_builtin(__builtin_amdgcn_exp2f)
    return __builtin_amdgcn_exp2f(x);
#else
    return __expf(x * 0.69314718055994531f);
#endif
}

// value from lane^1 (quad_perm [1,0,3,2]) — pure VALU, no LDS pipe
__device__ __forceinline__ float qswap(float x) {
#if __has_builtin(__builtin_amdgcn_mov_dpp)
    return __int_as_float(
        __builtin_amdgcn_mov_dpp(__float_as_int(x), 0xB1, 0xF, 0xF, true));
#else
    return __shfl_xor(x, 1, 64);
#endif
}

__device__ __forceinline__ h2 as_h2(unsigned int x) {
    return __builtin_bit_cast(h2, x);
}

// pack two f32 -> h2 with one v_cvt_pkrtz_f16_f32
__device__ __forceinline__ h2 pk2(float a, float b) {
#if __has_builtin(__builtin_amdgcn_cvt_pkrtz)
    return __builtin_bit_cast(h2, __builtin_amdgcn_cvt_pkrtz(a, b));
#else
    h2 r; r[0] = (_Float16)a; r[1] = (_Float16)b; return r;
#endif
}

__device__ __forceinline__ unsigned int pku(float a, float b) {
    return __builtin_bit_cast(unsigned int, pk2(a, b));
}

__global__ __launch_bounds__(NTHR, 4)
void meanshift_kernel(const float* __restrict__ E,
                      const float* __restrict__ lbw,
                      float* __restrict__ out)
{
    __shared__ u4v  tile[4 * PSTR];      // 32.1 KB (fp16, 8ch / 16B word)
    __shared__ float sqv[THs * RSTR];    // -0.5*NC*|p|^2, same indexing

    const int bz  = blockIdx.z;
    const int oh  = blockIdx.y * BH - PADp;    // staged row 0 = rel -2
    const int owc = blockIdx.x * BW;           // true tile col origin
    const int gw0 = owc - 4;                   // staged col 0 = rel -4
    const int tid = threadIdx.x;
    const int half = tid & 1;
    const int pix  = tid >> 1;
    const int px   = pix & (BW - 1);
    const int py   = pix >> 4;
    const int c0   = 2 * half;

    const float bwv = log1pf(__expf(lbw[0]));     // softplus
    const float cc2 = 1.0f / (2.0f * bwv * bwv);
    const float NCf = cc2 * 1.44269504f;          // w = 2^(-NC*dist^2)
    const float A2f = 2.0f * NCf;                 // coef on p.z
    const float MZC = -1.0f / (8.0f * NCf);       // mzz = MZC * |zs|^2_full

    const float* Eb = E + (size_t)bz * Dch * HWp;

    // ---- vectorized staging: 1 job/thread = 8ch x 4px ----
    if (tid < NJOB) {
        const int cc  = tid / (THs * 6);
        const int rem = tid - cc * (THs * 6);
        const int row = rem / 6;
        const int g   = rem - row * 6;
        const int gh  = oh + row;
        const int gwb = gw0 + 4 * g;

        float4 F0 = {0.f,0.f,0.f,0.f}, F1 = F0, F2 = F0, F3 = F0;
        float4 F4 = F0, F5 = F0, F6 = F0, F7 = F0;
        if ((unsigned)gh < (unsigned)HH) {
            const float* base = Eb + (size_t)(8 * cc) * HWp + gh * WW;
            if (gwb >= 0 && gwb + 4 <= WW) {      // aligned fast path
                F0 = *(const float4*)(base + 0 * (size_t)HWp + gwb);
                F1 = *(const float4*)(base + 1 * (size_t)HWp + gwb);
                F2 = *(const float4*)(base + 2 * (size_t)HWp + gwb);
                F3 = *(const float4*)(base + 3 * (size_t)HWp + gwb);
                F4 = *(const float4*)(base + 4 * (size_t)HWp + gwb);
                F5 = *(const float4*)(base + 5 * (size_t)HWp + gwb);
                F6 = *(const float4*)(base + 6 * (size_t)HWp + gwb);
                F7 = *(const float4*)(base + 7 * (size_t)HWp + gwb);
            } else {                               // edge: per-element
                const bool i0 = (unsigned)(gwb + 0) < (unsigned)WW;
                const bool i1 = (unsigned)(gwb + 1) < (unsigned)WW;
                const bool i2 = (unsigned)(gwb + 2) < (unsigned)WW;
                const bool i3 = (unsigned)(gwb + 3) < (unsigned)WW;
#define GE(K) F##K = make_float4( \
                    i0 ? base[(K) * (size_t)HWp + gwb + 0] : 0.f, \
                    i1 ? base[(K) * (size_t)HWp + gwb + 1] : 0.f, \
                    i2 ? base[(K) * (size_t)HWp + gwb + 2] : 0.f, \
                    i3 ? base[(K) * (size_t)HWp + gwb + 3] : 0.f)
                GE(0); GE(1); GE(2); GE(3); GE(4); GE(5); GE(6); GE(7);
#undef GE
            }
        }
        // register transpose: 4 pixels' 8-channel words
        const int wbase = cc * PSTR + row * RSTR + 4 * g;
        u4v W;
        W[0]=pku(F0.x,F1.x); W[1]=pku(F2.x,F3.x); W[2]=pku(F4.x,F5.x); W[3]=pku(F6.x,F7.x);
        tile[wbase + 0] = W;
        W[0]=pku(F0.y,F1.y); W[1]=pku(F2.y,F3.y); W[2]=pku(F4.y,F5.y); W[3]=pku(F6.y,F7.y);
        tile[wbase + 1] = W;
        W[0]=pku(F0.z,F1.z); W[1]=pku(F2.z,F3.z); W[2]=pku(F4.z,F5.z); W[3]=pku(F6.z,F7.z);
        tile[wbase + 2] = W;
        W[0]=pku(F0.w,F1.w); W[1]=pku(F2.w,F3.w); W[2]=pku(F4.w,F5.w); W[3]=pku(F6.w,F7.w);
        tile[wbase + 3] = W;
    }
    __syncthreads();

    // ---- precompute sqv = -0.5*NC*|p|^2 (all 32 ch), 1 pixel/thread ----
    if (tid < THs * 24) {
        const int row = tid / 24;
        const int col = tid - row * 24;
        const int p   = row * RSTR + col;
        const u4v t0 = tile[0 * PSTR + p], t1 = tile[1 * PSTR + p];
        const u4v t2 = tile[2 * PSTR + p], t3 = tile[3 * PSTR + p];
        float a0 = 0.f, a1 = 0.f, a2 = 0.f, a3 = 0.f;
        #pragma unroll
        for (int j = 0; j < 4; ++j) {
            const h2 q0 = as_h2(t0[j]); a0 = fdot2f(q0, q0, a0);
            const h2 q1 = as_h2(t1[j]); a1 = fdot2f(q1, q1, a1);
            const h2 q2 = as_h2(t2[j]); a2 = fdot2f(q2, q2, a2);
            const h2 q3 = as_h2(t3[j]); a3 = fdot2f(q3, q3, a3);
        }
        sqv[p] = -0.5f * NCf * ((a0 + a1) + (a2 + a3));
    }
    __syncthreads();

    const u4v* __restrict__ tA = tile + c0 * PSTR;
    const u4v* __restrict__ tB = tA + PSTR;

    // ---- init zs = A2 * z(own pixel), my 16 channels ----
    h2 zs0, zs1, zs2, zs3, zs4, zs5, zs6, zs7;
    {
        const int myp = (py + 2) * RSTR + (px + 4);   // center (rel col px)
        const u4v ca = tA[myp];
        const u4v cb = tB[myp];
        const h2 A2v = pk2(A2f, A2f);
        zs0 = as_h2(ca[0]) * A2v; zs1 = as_h2(ca[1]) * A2v;
        zs2 = as_h2(ca[2]) * A2v; zs3 = as_h2(ca[3]) * A2v;
        zs4 = as_h2(cb[0]) * A2v; zs5 = as_h2(cb[1]) * A2v;
        zs6 = as_h2(cb[2]) * A2v; zs7 = as_h2(cb[3]) * A2v;
    }

    float* Ob = out + (size_t)bz * Dch * HWp;
    const int off    = (oh + PADp + py) * WW + (owc + px);
    const int chbase = 16 * half;

#define NBODY(NPI) do {                                                       \
        const u4v a  = tA[(NPI)];                                             \
        const u4v bq = tB[(NPI)];                                             \
        const float Sv = sqv[(NPI)];                                          \
        const h2 pa0 = as_h2(a[0]),  pa1 = as_h2(a[1]);                       \
        const h2 pa2 = as_h2(a[2]),  pa3 = as_h2(a[3]);                       \
        const h2 pb0 = as_h2(bq[0]), pb1 = as_h2(bq[1]);                      \
        const h2 pb2 = as_h2(bq[2]), pb3 = as_h2(bq[3]);                      \
        float s0 = fdot2f(pa0, zs0, Sv);                                      \
        s0 = fdot2f(pa1, zs1, s0); s0 = fdot2f(pa2, zs2, s0);                 \
        s0 = fdot2f(pa3, zs3, s0);                                            \
        float s1 = fdot2f(pb0, zs4, mzz);                                     \
        s1 = fdot2f(pb1, zs5, s1); s1 = fdot2f(pb2, zs6, s1);                 \
        s1 = fdot2f(pb3, zs7, s1);                                            \
        const float dp  = s0 + s1;                                            \
        const float arg = dp + qswap(dp);   /* A2 p.z - NC|p|^2 - NC|z|^2 */  \
        const float w   = EXP2F(arg);       /* <= ~1 */                       \
        den += w;                                                             \
        const h2 w2v = pk2(w, w);                                             \
        n0 += pa0 * w2v; n1 += pa1 * w2v; n2 += pa2 * w2v; n3 += pa3 * w2v;   \
        n4 += pb0 * w2v; n5 += pb1 * w2v; n6 += pb2 * w2v; n7 += pb3 * w2v;   \
    } while (0)

    #pragma unroll 1
    for (int it = 0; it < ITERS; ++it) {
        // mzz = -0.5*NC*|z|^2 (full 32 ch), from |zs|^2 = A2^2 |z|^2
        float mzz;
        {
            float q0 = fdot2f(zs0, zs0, 0.f);
            q0 = fdot2f(zs1, zs1, q0); q0 = fdot2f(zs2, zs2, q0);
            q0 = fdot2f(zs3, zs3, q0);
            float q1 = fdot2f(zs4, zs4, 0.f);
            q1 = fdot2f(zs5, zs5, q1); q1 = fdot2f(zs6, zs6, q1);
            q1 = fdot2f(zs7, zs7, q1);
            const float qs = q0 + q1;
            mzz = (qs + qswap(qs)) * MZC;
        }

        h2 n0 = {(_Float16)0.f, (_Float16)0.f};
        h2 n1 = n0, n2 = n0, n3 = n0, n4 = n0, n5 = n0, n6 = n0, n7 = n0;
        float den = 0.f;

        #pragma unroll 1
        for (int di = 0; di < 5; ++di) {
            const int rb = (py + di) * RSTR + px + 2;   // rel cols px-2..px+2
            NBODY(rb + 0);
            NBODY(rb + 1);
            NBODY(rb + 2);
            NBODY(rb + 3);
            NBODY(rb + 4);
        }

        const float invf = 1.0f / (den + 1e-6f);
        if (it == ITERS - 1) {
#define WR(IDX, NV, EL) Ob[(size_t)(chbase + (IDX)) * HWp + off] = (float)NV[EL] * invf
            WR(0,  n0, 0); WR(1,  n0, 1); WR(2,  n1, 0); WR(3,  n1, 1);
            WR(4,  n2, 0); WR(5,  n2, 1); WR(6,  n3, 0); WR(7,  n3, 1);
            WR(8,  n4, 0); WR(9,  n4, 1); WR(10, n5, 0); WR(11, n5, 1);
            WR(12, n6, 0); WR(13, n6, 1); WR(14, n7, 0); WR(15, n7, 1);
#undef WR
        } else {
            // zs_new = A2 * (num * invf): fold A2 into the inverse
            const float ia = invf * A2f;
            const h2 iv = pk2(ia, ia);
            zs0 = n0 * iv; zs1 = n1 * iv; zs2 = n2 * iv; zs3 = n3 * iv;
            zs4 = n4 * iv; zs5 = n5 * iv; zs6 = n6 * iv; zs7 = n7 * iv;
        }
    }
#undef NBODY
}

extern "C" void kernel_launch(void* const* d_in, const int* in_sizes, int n_in,
                              void* d_out, int out_size, void* d_ws, size_t ws_size,
                              hipStream_t stream) {
    const float* E   = (const float*)d_in[0];
    const float* lbw = (const float*)d_in[1];
    float* out       = (float*)d_out;

    const int B = in_sizes[0] / (Dch * HWp);       // = 2
    dim3 grid(WW / BW, HH / BH, B);                // (16,16,2) = 512 blocks
    dim3 block(NTHR, 1, 1);                        // 512 threads (2/pixel)
    hipLaunchKernelGGL(meanshift_kernel, grid, block, 0, stream, E, lbw, out);
}